// Round 12
// baseline (287.235 us; speedup 1.0000x reference)
//
#include <hip/hip_runtime.h>
#include <hip/hip_bf16.h>
#include <cstdint>
#include <cstddef>

#define KDIM 4096   // IN_F
#define NDIM 4096   // OUT_F

typedef __attribute__((ext_vector_type(8))) short short8;
typedef __attribute__((ext_vector_type(8))) __bf16 bf16x8;
typedef __attribute__((ext_vector_type(4))) float f32x4;

// f32 -> bf16, round-to-nearest-even
__device__ __forceinline__ unsigned short bf16_rne(float f) {
    unsigned int u = __builtin_bit_cast(unsigned int, f);
    u += 0x7fffu + ((u >> 16) & 1u);
    return (unsigned short)(u >> 16);
}

__device__ __forceinline__ void gload_lds16(const unsigned short* g, unsigned short* l) {
    __builtin_amdgcn_global_load_lds(
        (const __attribute__((address_space(1))) unsigned int*)g,
        (__attribute__((address_space(3))) unsigned int*)l,
        16, 0, 0);
}

// ---------------- preprocess: x fp32 -> bf16 ----------------
__global__ void cvt_x_kernel(const float* __restrict__ x, unsigned short* __restrict__ xb) {
    long i = (long)blockIdx.x * blockDim.x + threadIdx.x;   // one thread = 8 elems
    float4 a = ((const float4*)x)[2 * i];
    float4 b = ((const float4*)x)[2 * i + 1];
    union { unsigned short u[8]; short8 v; } r;
    r.u[0] = bf16_rne(a.x); r.u[1] = bf16_rne(a.y);
    r.u[2] = bf16_rne(a.z); r.u[3] = bf16_rne(a.w);
    r.u[4] = bf16_rne(b.x); r.u[5] = bf16_rne(b.y);
    r.u[6] = bf16_rne(b.z); r.u[7] = bf16_rne(b.w);
    ((short8*)xb)[i] = r.v;
}

// ---------------- preprocess: dequant 2-bit W -> bf16 [N][K] ----------------
__global__ void dequant_w_kernel(const int* __restrict__ wp,
                                 const float* __restrict__ scales,
                                 const float* __restrict__ zeros,
                                 unsigned short* __restrict__ wb) {
    long i = (long)blockIdx.x * blockDim.x + threadIdx.x;   // one thread = 2 packed ints = 8 weights
    int2 p = ((const int2*)wp)[i];
    long base = i * 8;                    // flat weight index (o*4096 + k)
    int o = (int)(base >> 12);
    int g = (int)((base & 4095) >> 7);    // all 8 weights in same group (8 | 128)
    float s = scales[o * 32 + g];
    float z = zeros[o * 32 + g];
    union { unsigned short u[8]; short8 v; } r;
#pragma unroll
    for (int j = 0; j < 4; ++j) {
        r.u[j]     = bf16_rne((float)((p.x >> (2 * j)) & 3) * s + z);
        r.u[4 + j] = bf16_rne((float)((p.y >> (2 * j)) & 3) * s + z);
    }
    ((short8*)wb)[i] = r.v;
}

// ---------------- 256x256 8-phase GEMM, BALANCED READS 8/4/8/4 (R12) ----------------
// C[M][N] = A[M][K](bf16) * B[N][K](bf16)^T + bias.
// R12 = R11 with ONE change: the 12-read phase is rebalanced. bQ0 (B-n01) is
// read in the PREVIOUS tile's stage-phase (P4/P8, which had 0 reads), placed
// AFTER that phase's vmcnt+barrier (buffer provably resident there, per R11
// ledger). Read balance per tile: 12/4/8/0 -> 8/4/8/4. Theory: the 12-read
// burst (96 b128/CU ~ 768cy LDS) exceeded the 620cy MFMA hiding window; the
// 0-read phase wasted hiding capacity; balanced phases fit under the
// barrier-stagger envelope (m201's "4 or 8 reads/phase" rule).
//
// STAGE RING + VMCNT: identical to R11 (unchanged):
//  P1: A0(o),A1(o)->buf1.A | P3: B0(e2)->buf0.Bn01 | P4: B1(e2),A0(e2)->buf0
//   then VMCNT(6) => tile o fully resident | P5: A1(e2)->buf0.Ah1 |
//  P7: B0(o2)->buf1.Bn01 | P8: B1(o2)->buf1.Bn23 then VMCNT(4) => buf0(e+2)
//   resident. Prologue: tile0(8)->buf0, B(1)(4)->buf1, vmcnt(4).
// READ MAP (per wave):
//  P1: aF=A-h0 (8)      | MFMA Q00(aF,bQ0)   [bQ0 read at prev P8/prologue]
//  P2: bQ1=B-n23 (4)    | MFMA Q01(aF,bQ1)
//  P3: aG=A-h1 (8)      | MFMA Q10(aG,bQ0)
//  P4: [post-barrier] bQ0=B-n01(o) (4) | MFMA Q11(aG,bQ1)
//  P5-P8: mirror for tile o; P8 reads bQ0(e+2) post-barrier.
// LEDGER DELTAS (verified):
//  - bQ0 region (buf.Bn01) read at P8(prev); returns by P1's lgkm0 < P1-end
//    barrier < P3's stage overwrite. W-A-R ok.
//  - register WAR: bQ0 rewritten P4/P8 after last use P3/P7 (program order).
//  - ds_reads are lgkm, not vmcnt: vmcnt constants unaffected.
//  - P4/P8 reads sit after vmcnt+s_barrier => all waves' vmcnt passed =>
//    target buffer resident cross-wave.
//  - tail: e2/o2 clamped => byte-idempotent restage; P8 tail read is dead.
// Swizzle (proven, 0 conflicts): LDS(r,8j)=G(r,8*(j^(r&7))); read elem
//  R*64 + 8*((4s+lk4)^(R&7)), R&7 == lane&7.

#define PH_BAR_WAIT \
    __builtin_amdgcn_s_barrier(); \
    asm volatile("s_waitcnt lgkmcnt(0)" ::: "memory"); \
    __builtin_amdgcn_sched_barrier(0);

#define PH_END \
    __builtin_amdgcn_s_setprio(0); \
    __builtin_amdgcn_sched_barrier(0); \
    __builtin_amdgcn_s_barrier();

#define VMCNT(N) \
    __builtin_amdgcn_sched_barrier(0); \
    asm volatile("s_waitcnt vmcnt(" #N ")" ::: "memory"); \
    __builtin_amdgcn_sched_barrier(0);

#define RD_A(arr, DOFF, mh) \
    _Pragma("unroll") \
    for (int mi_ = 0; mi_ < 4; ++mi_) { \
        arr[mi_][0] = *(const short8*)&sm[(DOFF) + aBase + ((mh)*4 + mi_) * 1024 + sw0]; \
        arr[mi_][1] = *(const short8*)&sm[(DOFF) + aBase + ((mh)*4 + mi_) * 1024 + sw1]; \
    }

#define RD_B(bx, DOFF, n0) \
    _Pragma("unroll") \
    for (int ni_ = 0; ni_ < 2; ++ni_) { \
        bx[ni_][0] = *(const short8*)&sm[(DOFF) + bBase + ((n0) + ni_) * 1024 + sw0]; \
        bx[ni_][1] = *(const short8*)&sm[(DOFF) + bBase + ((n0) + ni_) * 1024 + sw1]; \
    }

#define QUADX(af, bx, mh, nh) \
    __builtin_amdgcn_s_setprio(1); \
    _Pragma("unroll") \
    for (int s_ = 0; s_ < 2; ++s_) { \
      _Pragma("unroll") \
      for (int mi_ = 0; mi_ < 4; ++mi_) { \
        _Pragma("unroll") \
        for (int ni_ = 0; ni_ < 2; ++ni_) { \
          acc[(mh)*4+mi_][(nh)*2+ni_] = __builtin_amdgcn_mfma_f32_16x16x32_bf16( \
            __builtin_bit_cast(bf16x8, af[mi_][s_]), \
            __builtin_bit_cast(bf16x8, bx[ni_][s_]), \
            acc[(mh)*4+mi_][(nh)*2+ni_], 0, 0, 0); \
        } } }

__global__ __launch_bounds__(512, 2) void gemm256(const unsigned short* __restrict__ A,
                                                  const unsigned short* __restrict__ B,
                                                  const float* __restrict__ bias,
                                                  float* __restrict__ C) {
    __shared__ __align__(16) unsigned short sm[65536];   // 128 KiB

    const int tid = threadIdx.x;
    const int w64 = tid >> 6;
    const int lane = tid & 63;

    // T1: bijective XCD swizzle (gridDim.x % 8 == 0)
    const int nwg = gridDim.x;
    const int chunk = nwg >> 3;
    const int s_id = (blockIdx.x & 7) * chunk + (blockIdx.x >> 3);
    const int nm = nwg >> 4;              // M tiles (N tiles fixed at 16)
    const int bm = s_id % nm;
    const int bn = s_id / nm;
    const int row0 = bm * 256;
    const int col0 = bn * 256;

    const int wr = w64 >> 2;              // 0..1 (M half: 128 rows)
    const int wc = w64 & 3;               // 0..3 (N quarter: 64 cols)

    // ---- stage addressing (proven): row srow(+64,+128h), swizzled k
    const int srow = tid >> 3;                                  // 0..63
    const int swzk = 8 * ((tid & 7) ^ ((tid >> 3) & 7));        // pre-swizzled src elem
    const unsigned short* srcA = A + (size_t)(row0 + srow) * KDIM + swzk;
    const unsigned short* srcB = B + (size_t)(col0 + srow) * KDIM + swzk;

    // ---- frag addressing (proven, 0 conflicts)
    const int lr = lane & 15;
    const int lk4 = lane >> 4;
    const int l7 = lane & 7;
    const int sw0 = 8 * (((0 << 2) + lk4) ^ l7);
    const int sw1 = 8 * (((1 << 2) + lk4) ^ l7);
    const int aBase = (wr * 128 + lr) * 64;
    const int bBase = 16384 + (wc * 64 + lr) * 64;

    f32x4 acc[8][4] = {};
    short8 aF[4][2], aG[4][2], bQ0[2][2], bQ1[2][2];

    auto stageA = [&](int hh, int tile, int db) {
        const unsigned short* g = srcA + (size_t)hh * 128 * KDIM + (size_t)tile * 64;
        unsigned short* l = &sm[db * 32768 + hh * 8192 + w64 * 512];
        gload_lds16(g, l);
        gload_lds16(g + (size_t)64 * KDIM, l + 4096);
    };
    auto stageB = [&](int hh, int tile, int db) {
        const unsigned short* g = srcB + (size_t)hh * 128 * KDIM + (size_t)tile * 64;
        unsigned short* l = &sm[db * 32768 + 16384 + hh * 8192 + w64 * 512];
        gload_lds16(g, l);
        gload_lds16(g + (size_t)64 * KDIM, l + 4096);
    };

    const int NT = KDIM / 64;   // 64 K-tiles (even)

    // ---- prologue: tile0 -> buf0 (8 loads), tile1.B -> buf1 (4 loads)
    stageB(0, 0, 0); stageB(1, 0, 0); stageA(0, 0, 0); stageA(1, 0, 0);
    stageB(0, 1, 1); stageB(1, 1, 1);
    VMCNT(4)                    // buf0 fully resident; B(1)4 in flight = invariant
    __builtin_amdgcn_s_barrier();
    RD_B(bQ0, 0, 0)             // bQ0(tile0): balanced pre-read (P8-slot analog)
    __builtin_amdgcn_sched_barrier(0);

    for (int i = 0; i < NT / 2; ++i) {
        const int e = 2 * i;
        const int o = e + 1;
        const int e2 = (e + 2 < NT) ? e + 2 : e;   // clamp: byte-idempotent restage
        const int o2 = (o + 2 < NT) ? o + 2 : o;

        // ===== P1: read aF=A-h0(e) [8]; stage A0(o),A1(o)->buf1; MFMA Q00 =====
        RD_A(aF, 0, 0)
        stageA(0, o, 1);
        stageA(1, o, 1);
        PH_BAR_WAIT
        QUADX(aF, bQ0, 0, 0)
        PH_END
        // ===== P2: read bQ1=B-n23(e) [4]; MFMA Q01 =====
        RD_B(bQ1, 0, 2)
        PH_BAR_WAIT
        QUADX(aF, bQ1, 0, 1)
        PH_END
        // ===== P3: read aG=A-h1(e) [8]; stage B0(e+2)->buf0; MFMA Q10 =====
        RD_A(aG, 0, 1)
        stageB(0, e2, 0);
        PH_BAR_WAIT
        QUADX(aG, bQ0, 1, 0)
        PH_END
        // ===== P4: stage B1(e+2),A0(e+2)->buf0; vmcnt(6) => tile o resident;
        //          post-barrier read bQ0(o) [4]; MFMA Q11 =====
        stageB(1, e2, 0);
        stageA(0, e2, 0);
        VMCNT(6)
        PH_BAR_WAIT
        RD_B(bQ0, 32768, 0)
        __builtin_amdgcn_sched_barrier(0);
        QUADX(aG, bQ1, 1, 1)
        PH_END

        // ===== P5: read aF(o) [8]; stage A1(e+2)->buf0; MFMA Q00(o) =====
        RD_A(aF, 32768, 0)
        stageA(1, e2, 0);
        PH_BAR_WAIT
        QUADX(aF, bQ0, 0, 0)
        PH_END
        // ===== P6: read bQ1(o) [4]; MFMA Q01(o) =====
        RD_B(bQ1, 32768, 2)
        PH_BAR_WAIT
        QUADX(aF, bQ1, 0, 1)
        PH_END
        // ===== P7: read aG(o) [8]; stage B0(o+2)->buf1; MFMA Q10(o) =====
        RD_A(aG, 32768, 1)
        stageB(0, o2, 1);
        PH_BAR_WAIT
        QUADX(aG, bQ0, 1, 0)
        PH_END
        // ===== P8: stage B1(o+2)->buf1; vmcnt(4) => buf0(e+2) resident;
        //          post-barrier read bQ0(e+2) [4]; MFMA Q11(o) =====
        stageB(1, o2, 1);
        VMCNT(4)
        PH_BAR_WAIT
        RD_B(bQ0, 0, 0)
        __builtin_amdgcn_sched_barrier(0);
        QUADX(aG, bQ1, 1, 1)
        PH_END
    }

    // no LDS-DMA / dangling reads may outlive the loop
    __builtin_amdgcn_sched_barrier(0);
    asm volatile("s_waitcnt vmcnt(0) lgkmcnt(0)" ::: "memory");
    __builtin_amdgcn_sched_barrier(0);

    // ---- epilogue: C/D layout col=lane&15, row=(lane>>4)*4+r
#pragma unroll
    for (int m = 0; m < 8; ++m) {
#pragma unroll
        for (int n = 0; n < 4; ++n) {
            int col = col0 + wc * 64 + n * 16 + lr;
            float bz = bias[col];
#pragma unroll
            for (int r = 0; r < 4; ++r) {
                int row = row0 + wr * 128 + m * 16 + lk4 * 4 + r;
                C[(size_t)row * NDIM + col] = acc[m][n][r] + bz;
            }
        }
    }
}

// ---------------- emergency fallback (ws too small / odd shape): exact fp32 ----------------
__global__ void fallback_kernel(const float* __restrict__ x, const int* __restrict__ wp,
                                const float* __restrict__ scales, const float* __restrict__ zeros,
                                const float* __restrict__ bias, float* __restrict__ out) {
    int o = blockIdx.x * 256 + threadIdx.x;
    int m = blockIdx.y;
    __shared__ float xs[KDIM];
    for (int i = threadIdx.x; i < KDIM; i += 256) xs[i] = x[(size_t)m * KDIM + i];
    __syncthreads();
    float acc = 0.f;
    for (int g = 0; g < 32; ++g) {
        float s = scales[o * 32 + g], z = zeros[o * 32 + g];
        float aq = 0.f, ax = 0.f;
        for (int j = 0; j < 32; ++j) {
            int p = wp[o * 1024 + g * 32 + j];
            int kb = g * 128 + j * 4;
#pragma unroll
            for (int q = 0; q < 4; ++q) {
                float xv = xs[kb + q];
                aq += xv * (float)((p >> (2 * q)) & 3);
                ax += xv;
            }
        }
        acc += s * aq + z * ax;
    }
    out[(size_t)m * NDIM + o] = acc + bias[o];
}

extern "C" void kernel_launch(void* const* d_in, const int* in_sizes, int n_in,
                              void* d_out, int out_size, void* d_ws, size_t ws_size,
                              hipStream_t stream) {
    const float* x      = (const float*)d_in[0];
    const int*   wp     = (const int*)d_in[1];
    const float* scales = (const float*)d_in[2];
    const float* zeros  = (const float*)d_in[3];
    const float* bias   = (const float*)d_in[4];
    float* out = (float*)d_out;

    const long M = (long)in_sizes[0] / KDIM;            // 8192
    const long PACKED = (long)in_sizes[1];              // 4194304
    const size_t need = (size_t)M * KDIM * 2 + (size_t)NDIM * KDIM * 2;  // 96 MB

    if (ws_size >= need && (M % 256) == 0) {
        unsigned short* xb = (unsigned short*)d_ws;
        unsigned short* wb = xb + (size_t)M * KDIM;
        cvt_x_kernel<<<(M * KDIM / 8) / 256, 256, 0, stream>>>(x, xb);
        dequant_w_kernel<<<(PACKED / 2) / 256, 256, 0, stream>>>(wp, scales, zeros, wb);
        int nwg = (int)(M / 256) * (NDIM / 256);        // 32*16 = 512, %8==0
        gemm256<<<nwg, 512, 0, stream>>>(xb, wb, bias, out);
    } else {
        dim3 grid(NDIM / 256, M);
        fallback_kernel<<<grid, 256, 0, stream>>>(x, wp, scales, zeros, bias, out);
    }
}

// Round 13
// 285.032 us; speedup vs baseline: 1.0077x; 1.0077x over previous
//
#include <hip/hip_runtime.h>
#include <hip/hip_bf16.h>
#include <cstdint>
#include <cstddef>

#define KDIM 4096   // IN_F
#define NDIM 4096   // OUT_F

typedef __attribute__((ext_vector_type(8))) short short8;
typedef __attribute__((ext_vector_type(8))) __bf16 bf16x8;
typedef __attribute__((ext_vector_type(4))) float f32x4;

// f32 -> bf16, round-to-nearest-even
__device__ __forceinline__ unsigned short bf16_rne(float f) {
    unsigned int u = __builtin_bit_cast(unsigned int, f);
    u += 0x7fffu + ((u >> 16) & 1u);
    return (unsigned short)(u >> 16);
}

__device__ __forceinline__ void gload_lds16(const unsigned short* g, unsigned short* l) {
    __builtin_amdgcn_global_load_lds(
        (const __attribute__((address_space(1))) unsigned int*)g,
        (__attribute__((address_space(3))) unsigned int*)l,
        16, 0, 0);
}

// ---------------- preprocess: x fp32 -> bf16 ----------------
__global__ void cvt_x_kernel(const float* __restrict__ x, unsigned short* __restrict__ xb) {
    long i = (long)blockIdx.x * blockDim.x + threadIdx.x;   // one thread = 8 elems
    float4 a = ((const float4*)x)[2 * i];
    float4 b = ((const float4*)x)[2 * i + 1];
    union { unsigned short u[8]; short8 v; } r;
    r.u[0] = bf16_rne(a.x); r.u[1] = bf16_rne(a.y);
    r.u[2] = bf16_rne(a.z); r.u[3] = bf16_rne(a.w);
    r.u[4] = bf16_rne(b.x); r.u[5] = bf16_rne(b.y);
    r.u[6] = bf16_rne(b.z); r.u[7] = bf16_rne(b.w);
    ((short8*)xb)[i] = r.v;
}

// ---------------- preprocess: dequant 2-bit W -> bf16 [N][K] ----------------
__global__ void dequant_w_kernel(const int* __restrict__ wp,
                                 const float* __restrict__ scales,
                                 const float* __restrict__ zeros,
                                 unsigned short* __restrict__ wb) {
    long i = (long)blockIdx.x * blockDim.x + threadIdx.x;   // one thread = 2 packed ints = 8 weights
    int2 p = ((const int2*)wp)[i];
    long base = i * 8;                    // flat weight index (o*4096 + k)
    int o = (int)(base >> 12);
    int g = (int)((base & 4095) >> 7);    // all 8 weights in same group (8 | 128)
    float s = scales[o * 32 + g];
    float z = zeros[o * 32 + g];
    union { unsigned short u[8]; short8 v; } r;
#pragma unroll
    for (int j = 0; j < 4; ++j) {
        r.u[j]     = bf16_rne((float)((p.x >> (2 * j)) & 3) * s + z);
        r.u[4 + j] = bf16_rne((float)((p.y >> (2 * j)) & 3) * s + z);
    }
    ((short8*)wb)[i] = r.v;
}

// ---------------- 256x256 8-phase GEMM, COMPILER-GATED DRAIN (R13) ----------------
// C[M][N] = A[M][K](bf16) * B[N][K](bf16)^T + bias.
// R13 = R12 with ONE change: NO explicit lgkmcnt(0)/sched_barrier between the
// leading s_barrier and the MFMA cluster. The phase's ds_reads are plain C++
// loads; the compiler gates each dependent MFMA with fine-grained lgkmcnt(N)
// (m97-verified), so the first MFMAs issue while later reads drain — hiding
// ~300-400cy/phase of serial drain that R7-R12 forced with the pinned
// lgkmcnt(0) (rule 18 applies only to inline-asm ds_reads, not ours).
//
// STAGE RING + VMCNT (R11/R12, unchanged):
//  P1: A0(o),A1(o)->buf1.A | P3: B0(e2)->buf0.Bn01 | P4: B1(e2),A0(e2)->buf0
//   then VMCNT(6) => tile o fully resident | P5: A1(e2)->buf0.Ah1 |
//  P7: B0(o2)->buf1.Bn01 | P8: B1(o2)->buf1.Bn23 then VMCNT(4) => buf0(e+2)
//   resident. Prologue: tile0(8)->buf0, B(1)(4)->buf1, vmcnt(4).
// READ MAP (8/4/8/4, R12): P1 aF; P2 bQ1; P3 aG; P4 post-barrier bQ0(next).
// W-A-R: every read consumed by its own phase's MFMA (data-dep => returned
//  before trailing barrier => before any overwriting stage). Register WAR:
//  bQ0 rewritten P4/P8 after last use P3/P7. Tail clamp => idempotent.
// Swizzle (proven, 0 conflicts): LDS(r,8j)=G(r,8*(j^(r&7))); read elem
//  R*64 + 8*((4s+lk4)^(R&7)), R&7 == lane&7.

#define PH_BAR \
    __builtin_amdgcn_s_barrier();

#define PH_END \
    __builtin_amdgcn_s_setprio(0); \
    __builtin_amdgcn_sched_barrier(0); \
    __builtin_amdgcn_s_barrier();

#define VMCNT(N) \
    __builtin_amdgcn_sched_barrier(0); \
    asm volatile("s_waitcnt vmcnt(" #N ")" ::: "memory"); \
    __builtin_amdgcn_sched_barrier(0);

#define RD_A(arr, DOFF, mh) \
    _Pragma("unroll") \
    for (int mi_ = 0; mi_ < 4; ++mi_) { \
        arr[mi_][0] = *(const short8*)&sm[(DOFF) + aBase + ((mh)*4 + mi_) * 1024 + sw0]; \
        arr[mi_][1] = *(const short8*)&sm[(DOFF) + aBase + ((mh)*4 + mi_) * 1024 + sw1]; \
    }

#define RD_B(bx, DOFF, n0) \
    _Pragma("unroll") \
    for (int ni_ = 0; ni_ < 2; ++ni_) { \
        bx[ni_][0] = *(const short8*)&sm[(DOFF) + bBase + ((n0) + ni_) * 1024 + sw0]; \
        bx[ni_][1] = *(const short8*)&sm[(DOFF) + bBase + ((n0) + ni_) * 1024 + sw1]; \
    }

#define QUADX(af, bx, mh, nh) \
    __builtin_amdgcn_s_setprio(1); \
    _Pragma("unroll") \
    for (int s_ = 0; s_ < 2; ++s_) { \
      _Pragma("unroll") \
      for (int mi_ = 0; mi_ < 4; ++mi_) { \
        _Pragma("unroll") \
        for (int ni_ = 0; ni_ < 2; ++ni_) { \
          acc[(mh)*4+mi_][(nh)*2+ni_] = __builtin_amdgcn_mfma_f32_16x16x32_bf16( \
            __builtin_bit_cast(bf16x8, af[mi_][s_]), \
            __builtin_bit_cast(bf16x8, bx[ni_][s_]), \
            acc[(mh)*4+mi_][(nh)*2+ni_], 0, 0, 0); \
        } } }

__global__ __launch_bounds__(512, 2) void gemm256(const unsigned short* __restrict__ A,
                                                  const unsigned short* __restrict__ B,
                                                  const float* __restrict__ bias,
                                                  float* __restrict__ C) {
    __shared__ __align__(16) unsigned short sm[65536];   // 128 KiB

    const int tid = threadIdx.x;
    const int w64 = tid >> 6;
    const int lane = tid & 63;

    // T1: bijective XCD swizzle (gridDim.x % 8 == 0)
    const int nwg = gridDim.x;
    const int chunk = nwg >> 3;
    const int s_id = (blockIdx.x & 7) * chunk + (blockIdx.x >> 3);
    const int nm = nwg >> 4;              // M tiles (N tiles fixed at 16)
    const int bm = s_id % nm;
    const int bn = s_id / nm;
    const int row0 = bm * 256;
    const int col0 = bn * 256;

    const int wr = w64 >> 2;              // 0..1 (M half: 128 rows)
    const int wc = w64 & 3;               // 0..3 (N quarter: 64 cols)

    // ---- stage addressing (proven): row srow(+64,+128h), swizzled k
    const int srow = tid >> 3;                                  // 0..63
    const int swzk = 8 * ((tid & 7) ^ ((tid >> 3) & 7));        // pre-swizzled src elem
    const unsigned short* srcA = A + (size_t)(row0 + srow) * KDIM + swzk;
    const unsigned short* srcB = B + (size_t)(col0 + srow) * KDIM + swzk;

    // ---- frag addressing (proven, 0 conflicts)
    const int lr = lane & 15;
    const int lk4 = lane >> 4;
    const int l7 = lane & 7;
    const int sw0 = 8 * (((0 << 2) + lk4) ^ l7);
    const int sw1 = 8 * (((1 << 2) + lk4) ^ l7);
    const int aBase = (wr * 128 + lr) * 64;
    const int bBase = 16384 + (wc * 64 + lr) * 64;

    f32x4 acc[8][4] = {};
    short8 aF[4][2], aG[4][2], bQ0[2][2], bQ1[2][2];

    auto stageA = [&](int hh, int tile, int db) {
        const unsigned short* g = srcA + (size_t)hh * 128 * KDIM + (size_t)tile * 64;
        unsigned short* l = &sm[db * 32768 + hh * 8192 + w64 * 512];
        gload_lds16(g, l);
        gload_lds16(g + (size_t)64 * KDIM, l + 4096);
    };
    auto stageB = [&](int hh, int tile, int db) {
        const unsigned short* g = srcB + (size_t)hh * 128 * KDIM + (size_t)tile * 64;
        unsigned short* l = &sm[db * 32768 + 16384 + hh * 8192 + w64 * 512];
        gload_lds16(g, l);
        gload_lds16(g + (size_t)64 * KDIM, l + 4096);
    };

    const int NT = KDIM / 64;   // 64 K-tiles (even)

    // ---- prologue: tile0 -> buf0 (8 loads), tile1.B -> buf1 (4 loads)
    stageB(0, 0, 0); stageB(1, 0, 0); stageA(0, 0, 0); stageA(1, 0, 0);
    stageB(0, 1, 1); stageB(1, 1, 1);
    VMCNT(4)                    // buf0 fully resident; B(1)4 in flight = invariant
    __builtin_amdgcn_s_barrier();
    RD_B(bQ0, 0, 0)             // bQ0(tile0): balanced pre-read

    for (int i = 0; i < NT / 2; ++i) {
        const int e = 2 * i;
        const int o = e + 1;
        const int e2 = (e + 2 < NT) ? e + 2 : e;   // clamp: byte-idempotent restage
        const int o2 = (o + 2 < NT) ? o + 2 : o;

        // ===== P1: read aF=A-h0(e) [8]; stage A0(o),A1(o)->buf1; MFMA Q00 =====
        RD_A(aF, 0, 0)
        stageA(0, o, 1);
        stageA(1, o, 1);
        PH_BAR
        QUADX(aF, bQ0, 0, 0)
        PH_END
        // ===== P2: read bQ1=B-n23(e) [4]; MFMA Q01 =====
        RD_B(bQ1, 0, 2)
        PH_BAR
        QUADX(aF, bQ1, 0, 1)
        PH_END
        // ===== P3: read aG=A-h1(e) [8]; stage B0(e+2)->buf0; MFMA Q10 =====
        RD_A(aG, 0, 1)
        stageB(0, e2, 0);
        PH_BAR
        QUADX(aG, bQ0, 1, 0)
        PH_END
        // ===== P4: stage B1(e+2),A0(e+2)->buf0; vmcnt(6) => tile o resident;
        //          post-barrier read bQ0(o) [4]; MFMA Q11 =====
        stageB(1, e2, 0);
        stageA(0, e2, 0);
        VMCNT(6)
        PH_BAR
        RD_B(bQ0, 32768, 0)
        QUADX(aG, bQ1, 1, 1)
        PH_END

        // ===== P5: read aF(o) [8]; stage A1(e+2)->buf0; MFMA Q00(o) =====
        RD_A(aF, 32768, 0)
        stageA(1, e2, 0);
        PH_BAR
        QUADX(aF, bQ0, 0, 0)
        PH_END
        // ===== P6: read bQ1(o) [4]; MFMA Q01(o) =====
        RD_B(bQ1, 32768, 2)
        PH_BAR
        QUADX(aF, bQ1, 0, 1)
        PH_END
        // ===== P7: read aG(o) [8]; stage B0(o+2)->buf1; MFMA Q10(o) =====
        RD_A(aG, 32768, 1)
        stageB(0, o2, 1);
        PH_BAR
        QUADX(aG, bQ0, 1, 0)
        PH_END
        // ===== P8: stage B1(o+2)->buf1; vmcnt(4) => buf0(e+2) resident;
        //          post-barrier read bQ0(e+2) [4]; MFMA Q11(o) =====
        stageB(1, o2, 1);
        VMCNT(4)
        PH_BAR
        RD_B(bQ0, 0, 0)
        QUADX(aG, bQ1, 1, 1)
        PH_END
    }

    // no LDS-DMA / dangling reads may outlive the loop
    __builtin_amdgcn_sched_barrier(0);
    asm volatile("s_waitcnt vmcnt(0) lgkmcnt(0)" ::: "memory");
    __builtin_amdgcn_sched_barrier(0);

    // ---- epilogue: C/D layout col=lane&15, row=(lane>>4)*4+r
#pragma unroll
    for (int m = 0; m < 8; ++m) {
#pragma unroll
        for (int n = 0; n < 4; ++n) {
            int col = col0 + wc * 64 + n * 16 + lr;
            float bz = bias[col];
#pragma unroll
            for (int r = 0; r < 4; ++r) {
                int row = row0 + wr * 128 + m * 16 + lk4 * 4 + r;
                C[(size_t)row * NDIM + col] = acc[m][n][r] + bz;
            }
        }
    }
}

// ---------------- emergency fallback (ws too small / odd shape): exact fp32 ----------------
__global__ void fallback_kernel(const float* __restrict__ x, const int* __restrict__ wp,
                                const float* __restrict__ scales, const float* __restrict__ zeros,
                                const float* __restrict__ bias, float* __restrict__ out) {
    int o = blockIdx.x * 256 + threadIdx.x;
    int m = blockIdx.y;
    __shared__ float xs[KDIM];
    for (int i = threadIdx.x; i < KDIM; i += 256) xs[i] = x[(size_t)m * KDIM + i];
    __syncthreads();
    float acc = 0.f;
    for (int g = 0; g < 32; ++g) {
        float s = scales[o * 32 + g], z = zeros[o * 32 + g];
        float aq = 0.f, ax = 0.f;
        for (int j = 0; j < 32; ++j) {
            int p = wp[o * 1024 + g * 32 + j];
            int kb = g * 128 + j * 4;
#pragma unroll
            for (int q = 0; q < 4; ++q) {
                float xv = xs[kb + q];
                aq += xv * (float)((p >> (2 * q)) & 3);
                ax += xv;
            }
        }
        acc += s * aq + z * ax;
    }
    out[(size_t)m * NDIM + o] = acc + bias[o];
}

extern "C" void kernel_launch(void* const* d_in, const int* in_sizes, int n_in,
                              void* d_out, int out_size, void* d_ws, size_t ws_size,
                              hipStream_t stream) {
    const float* x      = (const float*)d_in[0];
    const int*   wp     = (const int*)d_in[1];
    const float* scales = (const float*)d_in[2];
    const float* zeros  = (const float*)d_in[3];
    const float* bias   = (const float*)d_in[4];
    float* out = (float*)d_out;

    const long M = (long)in_sizes[0] / KDIM;            // 8192
    const long PACKED = (long)in_sizes[1];              // 4194304
    const size_t need = (size_t)M * KDIM * 2 + (size_t)NDIM * KDIM * 2;  // 96 MB

    if (ws_size >= need && (M % 256) == 0) {
        unsigned short* xb = (unsigned short*)d_ws;
        unsigned short* wb = xb + (size_t)M * KDIM;
        cvt_x_kernel<<<(M * KDIM / 8) / 256, 256, 0, stream>>>(x, xb);
        dequant_w_kernel<<<(PACKED / 2) / 256, 256, 0, stream>>>(wp, scales, zeros, wb);
        int nwg = (int)(M / 256) * (NDIM / 256);        // 32*16 = 512, %8==0
        gemm256<<<nwg, 512, 0, stream>>>(xb, wb, bias, out);
    } else {
        dim3 grid(NDIM / 256, M);
        fallback_kernel<<<grid, 256, 0, stream>>>(x, wp, scales, zeros, bias, out);
    }
}